// Round 1
// baseline (14610.773 us; speedup 1.0000x reference)
//
#include <hip/hip_runtime.h>
#include <cstdint>

#define T_DIM 2048
#define D_DIM 16

typedef float vf4 __attribute__((ext_vector_type(4)));

// ws float layout:
// [0,1024)    W1q   (row-major [k][j], k=0..31, j=0..31)
// [1024,1536) W2q   ([j][d], j=0..31, d=0..15)
// [1536,1568) b1
// [1568,1584) b2
// [1584,1616) inv_c
// [1616,1648) c_s
// [1648,1680) rho_s
// [1680,1712) L = 6*c_s

__global__ __launch_bounds__(256) void prep_kernel(
    const float* __restrict__ W1, const float* __restrict__ b1,
    const float* __restrict__ W2, const float* __restrict__ b2,
    const float* __restrict__ c,  const float* __restrict__ rho,
    float* __restrict__ wsp)
{
    __shared__ float red[256];
    const int t = threadIdx.x;

    // s1 = max(max|W1|, 1e-8) / 7
    float m = 0.0f;
    for (int i = t; i < 1024; i += 256) m = fmaxf(m, fabsf(W1[i]));
    red[t] = m;
    __syncthreads();
    for (int s = 128; s > 0; s >>= 1) {
        if (t < s) red[t] = fmaxf(red[t], red[t + s]);
        __syncthreads();
    }
    const float s1 = fmaxf(red[0], 1e-8f) / 7.0f;
    __syncthreads();

    // s2 = max(max|W2|, 1e-8) / 7
    m = 0.0f;
    for (int i = t; i < 512; i += 256) m = fmaxf(m, fabsf(W2[i]));
    red[t] = m;
    __syncthreads();
    for (int s = 128; s > 0; s >>= 1) {
        if (t < s) red[t] = fmaxf(red[t], red[t + s]);
        __syncthreads();
    }
    const float s2 = fmaxf(red[0], 1e-8f) / 7.0f;

    // W1q = q*s + (W - q*s)
    for (int i = t; i < 1024; i += 256) {
        const float w = W1[i];
        const float q = fminf(fmaxf(rintf(w / s1), -7.0f), 7.0f);
        const float qs = q * s1;
        const float resid = w - qs;
        wsp[i] = qs + resid;
    }
    for (int i = t; i < 512; i += 256) {
        const float w = W2[i];
        const float q = fminf(fmaxf(rintf(w / s2), -7.0f), 7.0f);
        const float qs = q * s2;
        const float resid = w - qs;
        wsp[1024 + i] = qs + resid;
    }
    if (t < 32) wsp[1536 + t] = b1[t];
    if (t < 16) wsp[1568 + t] = b2[t];
    if (t < 32) {
        const float cs = fmaxf(c[t], 0.1f);
        const float rs = fmaxf(rho[t], 0.0f);
        wsp[1584 + t] = 1.0f / cs;
        wsp[1616 + t] = cs;
        wsp[1648 + t] = rs;
        wsp[1680 + t] = 6.0f * cs;
    }
}

// One pair-op: cat = [ca|cb] (32 floats as 2x4 vf4), out o[4] (16 floats).
// All register arrays are vf4 with compile-time-constant indexing only.
__device__ __forceinline__ void pair_core(
    const vf4 (&ca)[4], const vf4 (&cb)[4], vf4 (&o)[4],
    const vf4* __restrict__ W1v, const vf4* __restrict__ W2v,
    const vf4* __restrict__ b1v, const vf4* __restrict__ b2v,
    const float* __restrict__ invcs, const float* __restrict__ css,
    const float* __restrict__ rhos, const float* __restrict__ Ls)
{
    vf4 acc[8];
#pragma unroll
    for (int m = 0; m < 8; ++m) acc[m] = b1v[m];

    // GEMM1: h = cat @ W1 + b1   (k outer, j inner over 8 vf4 accumulators)
#pragma unroll
    for (int k = 0; k < 32; ++k) {
        const float ck = (k < 16) ? ca[k >> 2][k & 3] : cb[(k - 16) >> 2][(k - 16) & 3];
#pragma unroll
        for (int m = 0; m < 8; ++m) {
            const vf4 w = W1v[k * 8 + m];
            vf4 a = acc[m];
#pragma unroll
            for (int e = 0; e < 4; ++e) a[e] = fmaf(ck, w[e], a[e]);
            acc[m] = a;
        }
    }

    // c19 activation, elementwise
#pragma unroll
    for (int m = 0; m < 8; ++m) {
        vf4 v = acc[m];
#pragma unroll
        for (int e = 0; e < 4; ++e) {
            const int j = m * 4 + e;
            const float xv = v[e];
            const float scaled = xv * invcs[j];
            const float nf = floorf(scaled);
            const float tt = scaled - nf;
            const float hh = tt * (1.0f - tt);
            const int ni = (int)nf;
            const float sgn = (ni & 1) ? -1.0f : 1.0f;
            float r = css[j] * (sgn * hh + rhos[j] * (hh * hh));
            const float Lj = Ls[j];
            r = (xv >= Lj) ? (xv - Lj) : r;
            r = (xv <= -Lj) ? (xv + Lj) : r;
            v[e] = r;
        }
        acc[m] = v;
    }

    // GEMM2: o = h @ W2 + b2
    vf4 ov[4];
#pragma unroll
    for (int m = 0; m < 4; ++m) ov[m] = b2v[m];
#pragma unroll
    for (int j = 0; j < 32; ++j) {
        const float aj = acc[j >> 2][j & 3];
#pragma unroll
        for (int m = 0; m < 4; ++m) {
            const vf4 w = W2v[j * 4 + m];
            vf4 t2 = ov[m];
#pragma unroll
            for (int e = 0; e < 4; ++e) t2[e] = fmaf(aj, w[e], t2[e]);
            ov[m] = t2;
        }
    }
#pragma unroll
    for (int m = 0; m < 4; ++m) o[m] = ov[m];
}

__global__ __launch_bounds__(256) void tree_kernel(
    const float* __restrict__ x, const float* __restrict__ wsp,
    float* __restrict__ out)
{
    __shared__ vf4 W1v[256];          // W1 row k -> W1v[k*8 + m]
    __shared__ vf4 W2v[128];          // W2 row j -> W2v[j*4 + m]
    __shared__ vf4 b1v[8];
    __shared__ vf4 b2v[4];
    __shared__ float invcs[32], css[32], rhos[32], Ls[32];
    __shared__ float nodes[16][512];  // feature-major: conflict-light

    const int t = threadIdx.x;
    const int n = blockIdx.x;

    {
        float* w1f = (float*)W1v;
        for (int i = t; i < 1024; i += 256) w1f[i] = wsp[i];
        float* w2f = (float*)W2v;
        for (int i = t; i < 512; i += 256) w2f[i] = wsp[1024 + i];
        if (t < 32) {
            ((float*)b1v)[t] = wsp[1536 + t];
            invcs[t] = wsp[1584 + t];
            css[t]   = wsp[1616 + t];
            rhos[t]  = wsp[1648 + t];
            Ls[t]    = wsp[1680 + t];
        }
        if (t < 16) ((float*)b2v)[t] = wsp[1568 + t];
    }
    __syncthreads();

    const float* __restrict__ xrow = x + (size_t)n * (T_DIM * D_DIM);

    // head: levels 0-1 in registers; each thread folds 4 timesteps per u
#pragma unroll 1
    for (int u = 0; u < 2; ++u) {
        const int g = u * 256 + t;                     // L1 node index (0..511)
        const vf4* __restrict__ src = (const vf4*)(xrow + (size_t)g * 64);
        vf4 ca[4], cb[4], r1[4], r2[4], nv[4];

#pragma unroll
        for (int m = 0; m < 4; ++m) ca[m] = src[m];
#pragma unroll
        for (int m = 0; m < 4; ++m) cb[m] = src[4 + m];
        pair_core(ca, cb, r1, W1v, W2v, b1v, b2v, invcs, css, rhos, Ls);

#pragma unroll
        for (int m = 0; m < 4; ++m) ca[m] = src[8 + m];
#pragma unroll
        for (int m = 0; m < 4; ++m) cb[m] = src[12 + m];
        pair_core(ca, cb, r2, W1v, W2v, b1v, b2v, invcs, css, rhos, Ls);

        pair_core(r1, r2, nv, W1v, W2v, b1v, b2v, invcs, css, rhos, Ls);

#pragma unroll
        for (int m = 0; m < 4; ++m)
#pragma unroll
            for (int e = 0; e < 4; ++e) nodes[m * 4 + e][g] = nv[m][e];
    }
    __syncthreads();

    // tail: levels with P = 256 .. 1 pairs
#pragma unroll 1
    for (int P = 256; P >= 1; P >>= 1) {
        vf4 ca[4], cb[4];
        const bool active = (t < P);
        if (active) {
#pragma unroll
            for (int d = 0; d < 16; ++d) {
                ca[d >> 2][d & 3] = nodes[d][2 * t];
                cb[d >> 2][d & 3] = nodes[d][2 * t + 1];
            }
        }
        __syncthreads();
        if (active) {
            vf4 nv[4];
            pair_core(ca, cb, nv, W1v, W2v, b1v, b2v, invcs, css, rhos, Ls);
            if (P > 1) {
#pragma unroll
                for (int m = 0; m < 4; ++m)
#pragma unroll
                    for (int e = 0; e < 4; ++e) nodes[m * 4 + e][t] = nv[m][e];
            } else {
#pragma unroll
                for (int m = 0; m < 4; ++m)
                    ((vf4*)out)[(size_t)n * 4 + m] = nv[m];
            }
        }
        __syncthreads();
    }
}

extern "C" void kernel_launch(void* const* d_in, const int* in_sizes, int n_in,
                              void* d_out, int out_size, void* d_ws, size_t ws_size,
                              hipStream_t stream) {
    const float* x   = (const float*)d_in[0];
    const float* W1  = (const float*)d_in[1];
    const float* b1  = (const float*)d_in[2];
    const float* W2  = (const float*)d_in[3];
    const float* b2  = (const float*)d_in[4];
    const float* c   = (const float*)d_in[5];
    const float* rho = (const float*)d_in[6];
    float* out = (float*)d_out;
    float* wsp = (float*)d_ws;

    const int N = in_sizes[0] / (T_DIM * D_DIM);   // 4096

    prep_kernel<<<1, 256, 0, stream>>>(W1, b1, W2, b2, c, rho, wsp);
    tree_kernel<<<N, 256, 0, stream>>>(x, wsp, out);
}

// Round 2
// 9795.059 us; speedup vs baseline: 1.4916x; 1.4916x over previous
//
#include <hip/hip_runtime.h>
#include <cstdint>

#define T_DIM 2048
#define D_DIM 16

typedef float vf4 __attribute__((ext_vector_type(4)));

// ws float layout:
// [0,1024)    W1q   (row-major [k][j], k=0..31, j=0..31)
// [1024,1536) W2q   ([j][d], j=0..31, d=0..15)
// [1536,1568) b1
// [1568,1584) b2
// [1584,1616) inv_c
// [1616,1648) c_s
// [1648,1680) rho_s
// [1680,1712) L = 6*c_s

__global__ __launch_bounds__(256) void prep_kernel(
    const float* __restrict__ W1, const float* __restrict__ b1,
    const float* __restrict__ W2, const float* __restrict__ b2,
    const float* __restrict__ c,  const float* __restrict__ rho,
    float* __restrict__ wsp)
{
    __shared__ float red[256];
    const int t = threadIdx.x;

    // s1 = max(max|W1|, 1e-8) / 7
    float m = 0.0f;
    for (int i = t; i < 1024; i += 256) m = fmaxf(m, fabsf(W1[i]));
    red[t] = m;
    __syncthreads();
    for (int s = 128; s > 0; s >>= 1) {
        if (t < s) red[t] = fmaxf(red[t], red[t + s]);
        __syncthreads();
    }
    const float s1 = fmaxf(red[0], 1e-8f) / 7.0f;
    __syncthreads();

    // s2 = max(max|W2|, 1e-8) / 7
    m = 0.0f;
    for (int i = t; i < 512; i += 256) m = fmaxf(m, fabsf(W2[i]));
    red[t] = m;
    __syncthreads();
    for (int s = 128; s > 0; s >>= 1) {
        if (t < s) red[t] = fmaxf(red[t], red[t + s]);
        __syncthreads();
    }
    const float s2 = fmaxf(red[0], 1e-8f) / 7.0f;

    // W1q = q*s + (W - q*s)
    for (int i = t; i < 1024; i += 256) {
        const float w = W1[i];
        const float q = fminf(fmaxf(rintf(w / s1), -7.0f), 7.0f);
        const float qs = q * s1;
        const float resid = w - qs;
        wsp[i] = qs + resid;
    }
    for (int i = t; i < 512; i += 256) {
        const float w = W2[i];
        const float q = fminf(fmaxf(rintf(w / s2), -7.0f), 7.0f);
        const float qs = q * s2;
        const float resid = w - qs;
        wsp[1024 + i] = qs + resid;
    }
    if (t < 32) wsp[1536 + t] = b1[t];
    if (t < 16) wsp[1568 + t] = b2[t];
    if (t < 32) {
        const float cs = fmaxf(c[t], 0.1f);
        const float rs = fmaxf(rho[t], 0.0f);
        wsp[1584 + t] = 1.0f / cs;
        wsp[1616 + t] = cs;
        wsp[1648 + t] = rs;
        wsp[1680 + t] = 6.0f * cs;
    }
}

__device__ __forceinline__ vf4 fma4(float a, vf4 w, vf4 c) {
    vf4 r;
    r.x = fmaf(a, w.x, c.x);
    r.y = fmaf(a, w.y, c.y);
    r.z = fmaf(a, w.z, c.z);
    r.w = fmaf(a, w.w, c.w);
    return r;
}

// ---- pair-op over NAMED vf4 variables only (no thread-private arrays) ----
// inputs: A0..A7 (cat[32]); outputs: O0..O3 (o[16]); clobbers C0..C7.

#define G1K(CK, K) { const float ck_ = (CK); \
    C0 = fma4(ck_, W1v[(K)*8+0], C0); \
    C1 = fma4(ck_, W1v[(K)*8+1], C1); \
    C2 = fma4(ck_, W1v[(K)*8+2], C2); \
    C3 = fma4(ck_, W1v[(K)*8+3], C3); \
    C4 = fma4(ck_, W1v[(K)*8+4], C4); \
    C5 = fma4(ck_, W1v[(K)*8+5], C5); \
    C6 = fma4(ck_, W1v[(K)*8+6], C6); \
    C7 = fma4(ck_, W1v[(K)*8+7], C7); }

#define G1V(AV, KB) G1K((AV).x, (KB)) G1K((AV).y, (KB)+1) G1K((AV).z, (KB)+2) G1K((AV).w, (KB)+3)

#define ACTE(CV, E, J) { \
    const vf4  ap = actp[(J)];            /* {inv_c, c_s, rho_s, L} */ \
    const float xv = (CV).E; \
    const float sc = xv * ap.x; \
    const float nf = floorf(sc); \
    const float tt = sc - nf; \
    const float hh = tt * (1.0f - tt); \
    const int   ni = (int)nf; \
    const float sgn = (ni & 1) ? -1.0f : 1.0f; \
    float r = ap.y * (sgn * hh + ap.z * (hh * hh)); \
    const float Lj = ap.w; \
    r = (xv >= Lj) ? (xv - Lj) : r; \
    r = (xv <= -Lj) ? (xv + Lj) : r; \
    (CV).E = r; }

#define ACTV(CV, JB) ACTE(CV, x, (JB)) ACTE(CV, y, (JB)+1) ACTE(CV, z, (JB)+2) ACTE(CV, w, (JB)+3)

#define G2K(AJ, J) { const float aj_ = (AJ); \
    O0 = fma4(aj_, W2v[(J)*4+0], O0); \
    O1 = fma4(aj_, W2v[(J)*4+1], O1); \
    O2 = fma4(aj_, W2v[(J)*4+2], O2); \
    O3 = fma4(aj_, W2v[(J)*4+3], O3); }

#define G2V(CV, JB) G2K((CV).x, (JB)) G2K((CV).y, (JB)+1) G2K((CV).z, (JB)+2) G2K((CV).w, (JB)+3)

#define PAIR_BODY \
    C0 = b1v[0]; C1 = b1v[1]; C2 = b1v[2]; C3 = b1v[3]; \
    C4 = b1v[4]; C5 = b1v[5]; C6 = b1v[6]; C7 = b1v[7]; \
    G1V(A0, 0)  G1V(A1, 4)  G1V(A2, 8)  G1V(A3, 12) \
    G1V(A4, 16) G1V(A5, 20) G1V(A6, 24) G1V(A7, 28) \
    ACTV(C0, 0)  ACTV(C1, 4)  ACTV(C2, 8)  ACTV(C3, 12) \
    ACTV(C4, 16) ACTV(C5, 20) ACTV(C6, 24) ACTV(C7, 28) \
    O0 = b2v[0]; O1 = b2v[1]; O2 = b2v[2]; O3 = b2v[3]; \
    G2V(C0, 0)  G2V(C1, 4)  G2V(C2, 8)  G2V(C3, 12) \
    G2V(C4, 16) G2V(C5, 20) G2V(C6, 24) G2V(C7, 28)

__global__ __launch_bounds__(256) void tree_kernel(
    const float* __restrict__ x, const float* __restrict__ wsp,
    float* __restrict__ out)
{
    __shared__ vf4 W1v[256];          // W1 row k -> W1v[k*8 + m]
    __shared__ vf4 W2v[128];          // W2 row j -> W2v[j*4 + m]
    __shared__ vf4 b1v[8];
    __shared__ vf4 b2v[4];
    __shared__ vf4 actp[32];          // per-j {inv_c, c_s, rho_s, L}
    __shared__ float nodes[16][512];  // feature-major

    const int t = threadIdx.x;
    const int n = blockIdx.x;

    {
        float* w1f = (float*)W1v;
        for (int i = t; i < 1024; i += 256) w1f[i] = wsp[i];
        float* w2f = (float*)W2v;
        for (int i = t; i < 512; i += 256) w2f[i] = wsp[1024 + i];
        if (t < 32) ((float*)b1v)[t] = wsp[1536 + t];
        if (t < 16) ((float*)b2v)[t] = wsp[1568 + t];
        if (t < 32) {
            vf4 ap;
            ap.x = wsp[1584 + t];
            ap.y = wsp[1616 + t];
            ap.z = wsp[1648 + t];
            ap.w = wsp[1680 + t];
            actp[t] = ap;
        }
    }
    __syncthreads();

    const float* __restrict__ xrow = x + (size_t)n * (T_DIM * D_DIM);

    vf4 A0, A1, A2, A3, A4, A5, A6, A7;
    vf4 C0, C1, C2, C3, C4, C5, C6, C7;
    vf4 O0, O1, O2, O3;
    vf4 R0, R1, R2, R3, R4, R5, R6, R7;

    // head: levels 0-1; each thread folds 4 timesteps (3 pair-ops) per u
#pragma unroll 1
    for (int u = 0; u < 2; ++u) {
        const int g = u * 256 + t;                     // L1 node index (0..511)
        const vf4* __restrict__ src = (const vf4*)(xrow + (size_t)g * 64);
#pragma unroll 1
        for (int pp = 0; pp < 3; ++pp) {
            if (pp == 0) {
                A0 = src[0]; A1 = src[1]; A2 = src[2]; A3 = src[3];
                A4 = src[4]; A5 = src[5]; A6 = src[6]; A7 = src[7];
            } else if (pp == 1) {
                A0 = src[8];  A1 = src[9];  A2 = src[10]; A3 = src[11];
                A4 = src[12]; A5 = src[13]; A6 = src[14]; A7 = src[15];
            } else {
                A0 = R0; A1 = R1; A2 = R2; A3 = R3;
                A4 = R4; A5 = R5; A6 = R6; A7 = R7;
            }
            PAIR_BODY;
            if (pp == 0)      { R0 = O0; R1 = O1; R2 = O2; R3 = O3; }
            else if (pp == 1) { R4 = O0; R5 = O1; R6 = O2; R7 = O3; }
        }
        nodes[0][g]  = O0.x; nodes[1][g]  = O0.y; nodes[2][g]  = O0.z; nodes[3][g]  = O0.w;
        nodes[4][g]  = O1.x; nodes[5][g]  = O1.y; nodes[6][g]  = O1.z; nodes[7][g]  = O1.w;
        nodes[8][g]  = O2.x; nodes[9][g]  = O2.y; nodes[10][g] = O2.z; nodes[11][g] = O2.w;
        nodes[12][g] = O3.x; nodes[13][g] = O3.y; nodes[14][g] = O3.z; nodes[15][g] = O3.w;
    }
    __syncthreads();

    // tail: levels with P = 256 .. 1 pairs
#pragma unroll 1
    for (int P = 256; P >= 1; P >>= 1) {
        const bool active = (t < P);
        if (active) {
            const int i2 = 2 * t;
            A0.x = nodes[0][i2];  A0.y = nodes[1][i2];  A0.z = nodes[2][i2];  A0.w = nodes[3][i2];
            A1.x = nodes[4][i2];  A1.y = nodes[5][i2];  A1.z = nodes[6][i2];  A1.w = nodes[7][i2];
            A2.x = nodes[8][i2];  A2.y = nodes[9][i2];  A2.z = nodes[10][i2]; A2.w = nodes[11][i2];
            A3.x = nodes[12][i2]; A3.y = nodes[13][i2]; A3.z = nodes[14][i2]; A3.w = nodes[15][i2];
            const int i3 = i2 + 1;
            A4.x = nodes[0][i3];  A4.y = nodes[1][i3];  A4.z = nodes[2][i3];  A4.w = nodes[3][i3];
            A5.x = nodes[4][i3];  A5.y = nodes[5][i3];  A5.z = nodes[6][i3];  A5.w = nodes[7][i3];
            A6.x = nodes[8][i3];  A6.y = nodes[9][i3];  A6.z = nodes[10][i3]; A6.w = nodes[11][i3];
            A7.x = nodes[12][i3]; A7.y = nodes[13][i3]; A7.z = nodes[14][i3]; A7.w = nodes[15][i3];
        }
        __syncthreads();
        if (active) {
            PAIR_BODY;
            if (P > 1) {
                nodes[0][t]  = O0.x; nodes[1][t]  = O0.y; nodes[2][t]  = O0.z; nodes[3][t]  = O0.w;
                nodes[4][t]  = O1.x; nodes[5][t]  = O1.y; nodes[6][t]  = O1.z; nodes[7][t]  = O1.w;
                nodes[8][t]  = O2.x; nodes[9][t]  = O2.y; nodes[10][t] = O2.z; nodes[11][t] = O2.w;
                nodes[12][t] = O3.x; nodes[13][t] = O3.y; nodes[14][t] = O3.z; nodes[15][t] = O3.w;
            } else {
                vf4* __restrict__ op = (vf4*)(out + (size_t)n * 16);
                op[0] = O0; op[1] = O1; op[2] = O2; op[3] = O3;
            }
        }
        __syncthreads();
    }
}

extern "C" void kernel_launch(void* const* d_in, const int* in_sizes, int n_in,
                              void* d_out, int out_size, void* d_ws, size_t ws_size,
                              hipStream_t stream) {
    const float* x   = (const float*)d_in[0];
    const float* W1  = (const float*)d_in[1];
    const float* b1  = (const float*)d_in[2];
    const float* W2  = (const float*)d_in[3];
    const float* b2  = (const float*)d_in[4];
    const float* c   = (const float*)d_in[5];
    const float* rho = (const float*)d_in[6];
    float* out = (float*)d_out;
    float* wsp = (float*)d_ws;

    const int N = in_sizes[0] / (T_DIM * D_DIM);   // 4096

    prep_kernel<<<1, 256, 0, stream>>>(W1, b1, W2, b2, c, rho, wsp);
    tree_kernel<<<N, 256, 0, stream>>>(x, wsp, out);
}